// Round 1
// baseline (114.822 us; speedup 1.0000x reference)
//
#include <hip/hip_runtime.h>

// W2LossConst: per-trace  sum_i w_i * (t_i - spline_b(F_b[t_i]))^2 * f_b[t_i] * dt
//   F = cumulative trapezoid of f  ==  (inclusive_prefix(f) - 0.5*(f0 + f_i)) * dt
//   spline: piecewise cubic over monotone knots; F monotone -> forward-walk search.
//
// One 256-thread block per trace; each thread owns 32 contiguous samples in
// registers (f read from HBM exactly once). Block scan = wave shfl scan + LDS
// combine of 4 wave sums. Knots/coeffs staged in LDS; coeff float4 cached in
// registers and reloaded only when the interval index advances (~127 advances
// per 8192 samples -> ~0 steady-state LDS traffic).

#define NT 8192
#define K 128
#define NTHREADS 256
#define ELEMS (NT / NTHREADS) // 32 samples per thread

__global__ __launch_bounds__(NTHREADS) void w2loss_kernel(
    const float* __restrict__ f,
    const float* __restrict__ t,
    const float* __restrict__ knots,
    const float* __restrict__ coeffs,
    float* __restrict__ out)
{
    const int b    = blockIdx.x;
    const int tid  = threadIdx.x;
    const int lane = tid & 63;
    const int wave = tid >> 6;

    __shared__ float  s_knots[K];
    __shared__ float4 s_coeffs[K - 1];
    __shared__ float  s_wsum[NTHREADS / 64];
    __shared__ float  s_wred[NTHREADS / 64];
    __shared__ float  s_f0;

    // ---- stage per-trace spline tables in LDS ----
    if (tid < K) s_knots[tid] = knots[(size_t)b * K + tid];
    if (tid < K - 1)
        s_coeffs[tid] =
            reinterpret_cast<const float4*>(coeffs + (size_t)b * (K - 1) * 4)[tid];

    // ---- load this thread's 32 contiguous f samples into registers ----
    const float* fb = f + (size_t)b * NT + tid * ELEMS;
    const float4* fb4 = reinterpret_cast<const float4*>(fb);
    float fv[ELEMS];
#pragma unroll
    for (int i = 0; i < ELEMS / 4; ++i) {
        float4 v = fb4[i];
        fv[4 * i + 0] = v.x; fv[4 * i + 1] = v.y;
        fv[4 * i + 2] = v.z; fv[4 * i + 3] = v.w;
    }

    float local = 0.f;
#pragma unroll
    for (int i = 0; i < ELEMS; ++i) local += fv[i];

    // ---- inclusive wave scan of per-thread sums ----
    float scan = local;
#pragma unroll
    for (int d = 1; d < 64; d <<= 1) {
        float up = __shfl_up(scan, d, 64);
        if (lane >= d) scan += up;
    }
    if (lane == 63) s_wsum[wave] = scan;
    if (tid == 0)  s_f0 = fv[0];
    __syncthreads();

    float waveoff = 0.f;
#pragma unroll
    for (int w = 0; w < NTHREADS / 64; ++w)
        if (w < wave) waveoff += s_wsum[w];

    float S = waveoff + (scan - local);       // exclusive prefix of f for this thread
    const float f0 = s_f0;
    const float dt = t[1] - t[0];             // uniform grid; t_i == i*dt bit-exact

    // ---- spline eval + weighted accumulate ----
    float acc = 0.f;
    const int base = tid * ELEMS;
    int    idx;
    float  kn_lo, kn_hi;
    float4 c;

    { // first sample: 7-step ladder search (F monotone -> later samples walk)
        S += fv[0];
        float q = (S - 0.5f * (f0 + fv[0])) * dt;
        int p = 0;
#pragma unroll
        for (int step = 64; step >= 1; step >>= 1) {
            int np = p + step;
            if (np <= K - 1 && s_knots[np] <= q) p = np;
        }
        idx   = min(p, K - 2);
        kn_lo = s_knots[idx];
        kn_hi = s_knots[idx + 1];
        c     = s_coeffs[idx];
        float dx = q - kn_lo;
        float sp = c.x + dx * (c.y + dx * (c.z + dx * c.w));
        float tt = (float)base * dt;
        float d0 = tt - sp;
        float w0 = (base == 0) ? 0.5f : 1.0f;
        acc += w0 * d0 * d0 * fv[0];
    }

#pragma unroll
    for (int i = 1; i < ELEMS; ++i) {
        S += fv[i];
        float q = (S - 0.5f * (f0 + fv[i])) * dt;
        if (kn_hi <= q && idx < K - 2) {      // advance interval (rare)
            do { ++idx; kn_hi = s_knots[idx + 1]; } while (kn_hi <= q && idx < K - 2);
            kn_lo = s_knots[idx];
            c     = s_coeffs[idx];
        }
        float dx = q - kn_lo;
        float sp = c.x + dx * (c.y + dx * (c.z + dx * c.w));
        float tt = (float)(base + i) * dt;
        float d  = tt - sp;
        float wgt = ((base + i) == NT - 1) ? 0.5f : 1.0f;
        acc += wgt * d * d * fv[i];
    }

    // ---- block reduction ----
#pragma unroll
    for (int d = 32; d >= 1; d >>= 1) acc += __shfl_down(acc, d, 64);
    if (lane == 0) s_wred[wave] = acc;
    __syncthreads();
    if (tid == 0) {
        float r = 0.f;
#pragma unroll
        for (int w = 0; w < NTHREADS / 64; ++w) r += s_wred[w];
        out[b] = r * dt;
    }
}

extern "C" void kernel_launch(void* const* d_in, const int* in_sizes, int n_in,
                              void* d_out, int out_size, void* d_ws, size_t ws_size,
                              hipStream_t stream) {
    const float* f      = (const float*)d_in[0];
    const float* t      = (const float*)d_in[1];
    const float* knots  = (const float*)d_in[2];
    const float* coeffs = (const float*)d_in[3];
    float* out          = (float*)d_out;

    const int Btr = in_sizes[0] / NT;   // 2048 traces
    w2loss_kernel<<<Btr, NTHREADS, 0, stream>>>(f, t, knots, coeffs, out);
}

// Round 2
// 106.758 us; speedup vs baseline: 1.0755x; 1.0755x over previous
//
#include <hip/hip_runtime.h>

// W2LossConst: per-trace  sum_i w_i * (t_i - spline_b(F_b[t_i]))^2 * f_b[t_i] * dt
//   F = cumulative trapezoid of f. Within a thread, F evolves by the exact
//   trapezoid recurrence F += 0.5*dt*(f[i-1]+f[i]); the thread's starting F
//   comes from a block prefix-scan of per-thread f sums.
//   F monotone (f>0) -> spline search is one 7-step ladder + forward walk;
//   coeffs cached in registers, reloaded only on interval advance.
//
// 512 threads/block, 16 samples/thread (fv[16] keeps VGPRs low -> 8 waves/SIMD).
// f read from HBM/L3 exactly once, coalesced float4.

#define NT 8192
#define K 128
#define NTHREADS 512
#define ELEMS (NT / NTHREADS)   // 16 samples per thread
#define NWAVES (NTHREADS / 64)  // 8 waves

__global__ __launch_bounds__(NTHREADS) void w2loss_kernel(
    const float* __restrict__ f,
    const float* __restrict__ t,
    const float* __restrict__ knots,
    const float* __restrict__ coeffs,
    float* __restrict__ out)
{
    const int b    = blockIdx.x;
    const int tid  = threadIdx.x;
    const int lane = tid & 63;
    const int wave = tid >> 6;

    __shared__ float  s_knots[K];
    __shared__ float4 s_coeffs[K - 1];
    __shared__ float  s_wsum[NWAVES];
    __shared__ float  s_wred[NWAVES];
    __shared__ float  s_f0;

    // ---- stage per-trace spline tables in LDS ----
    if (tid < K) s_knots[tid] = knots[(size_t)b * K + tid];
    if (tid < K - 1)
        s_coeffs[tid] =
            reinterpret_cast<const float4*>(coeffs + (size_t)b * (K - 1) * 4)[tid];

    // ---- load this thread's 16 contiguous f samples into registers ----
    const float4* fb4 =
        reinterpret_cast<const float4*>(f + (size_t)b * NT + tid * ELEMS);
    float fv[ELEMS];
#pragma unroll
    for (int i = 0; i < ELEMS / 4; ++i) {
        float4 v = fb4[i];
        fv[4 * i + 0] = v.x; fv[4 * i + 1] = v.y;
        fv[4 * i + 2] = v.z; fv[4 * i + 3] = v.w;
    }

    float local = 0.f;
#pragma unroll
    for (int i = 0; i < ELEMS; ++i) local += fv[i];

    // ---- inclusive wave scan of per-thread sums ----
    float scan = local;
#pragma unroll
    for (int d = 1; d < 64; d <<= 1) {
        float up = __shfl_up(scan, d, 64);
        if (lane >= d) scan += up;
    }
    if (lane == 63) s_wsum[wave] = scan;
    if (tid == 0)  s_f0 = fv[0];
    __syncthreads();

    float waveoff = 0.f;
#pragma unroll
    for (int w = 0; w < NWAVES; ++w)
        if (w < wave) waveoff += s_wsum[w];

    const float f0      = s_f0;
    const float dt      = t[1] - t[0];       // uniform grid; t_i == i*dt
    const float half_dt = 0.5f * dt;

    // thread's first-sample CDF value from the block scan
    const float S_incl_first = waveoff + (scan - local) + fv[0];
    float F = (S_incl_first - 0.5f * (f0 + fv[0])) * dt;

    const int   base = tid * ELEMS;
    const float tb   = (float)base * dt;

    // ---- 7-step ladder search for the first sample's interval ----
    int idx = 0;
#pragma unroll
    for (int step = 64; step >= 1; step >>= 1) {
        int np = idx + step;
        if (np <= K - 1 && s_knots[np] <= F) idx = np;
    }
    if (idx > K - 2) idx = K - 2;
    float  kn_hi = s_knots[idx + 1];
    float  kn_lo = s_knots[idx];
    float4 c     = s_coeffs[idx];

    float acc, term_first, term_last = 0.f;
    {
        float dx = F - kn_lo;
        float sp = c.x + dx * (c.y + dx * (c.z + dx * c.w));
        float d0 = tb - sp;
        term_first = d0 * d0 * fv[0];
        acc = term_first;
    }

#pragma unroll
    for (int i = 1; i < ELEMS; ++i) {
        F = fmaf(fv[i - 1] + fv[i], half_dt, F);   // exact trapezoid recurrence
        if (kn_hi <= F) {                          // advance interval (rare)
            while (kn_hi <= F && idx < K - 2) { ++idx; kn_hi = s_knots[idx + 1]; }
            kn_lo = s_knots[idx];
            c     = s_coeffs[idx];
        }
        float dx = F - kn_lo;
        float sp = c.x + dx * (c.y + dx * (c.z + dx * c.w));
        float tt = fmaf((float)i, dt, tb);
        float d  = tt - sp;
        float term = d * d * fv[i];
        acc += term;
        if (i == ELEMS - 1) term_last = term;
    }

    // endpoint trapezoid weights (0.5) applied as post-corrections
    if (base == 0)          acc -= 0.5f * term_first;
    if (base + ELEMS == NT) acc -= 0.5f * term_last;

    // ---- block reduction ----
#pragma unroll
    for (int d = 32; d >= 1; d >>= 1) acc += __shfl_down(acc, d, 64);
    if (lane == 0) s_wred[wave] = acc;
    __syncthreads();
    if (tid == 0) {
        float r = 0.f;
#pragma unroll
        for (int w = 0; w < NWAVES; ++w) r += s_wred[w];
        out[b] = r * dt;
    }
}

extern "C" void kernel_launch(void* const* d_in, const int* in_sizes, int n_in,
                              void* d_out, int out_size, void* d_ws, size_t ws_size,
                              hipStream_t stream) {
    const float* f      = (const float*)d_in[0];
    const float* t      = (const float*)d_in[1];
    const float* knots  = (const float*)d_in[2];
    const float* coeffs = (const float*)d_in[3];
    float* out          = (float*)d_out;

    const int Btr = in_sizes[0] / NT;   // 2048 traces
    w2loss_kernel<<<Btr, NTHREADS, 0, stream>>>(f, t, knots, coeffs, out);
}

// Round 4
// 106.417 us; speedup vs baseline: 1.0790x; 1.0032x over previous
//
#include <hip/hip_runtime.h>

// W2LossConst: per-trace  sum_i w_i * (t_i - spline_b(F_b[t_i]))^2 * f_b[t_i] * dt
//   F = cumulative trapezoid of f; thread-local exact recurrence
//   F += 0.5*dt*(f[i-1]+f[i]) seeded from a block prefix-scan of f sums.
//   F monotone (f>0) -> interval search = 1 LUT probe + short forward walk.
//
// 1024 threads/block, 8 samples/thread. __launch_bounds__(1024,8) caps VGPR
// at 64 -> 8 waves/SIMD (occupancy halves at VGPR>64). A 256-cell uniform
// LUT over [0,1] (built once per block by 256 lanes) replaces the per-thread
// 7-dependent-LDS-read ladder (~840cyc serial) with ~1 dependent read.

#define NT 8192
#define K 128
#define NTHREADS 1024
#define ELEMS (NT / NTHREADS)   // 8 samples per thread
#define NWAVES (NTHREADS / 64)  // 16 waves
#define LUTG 256                // uniform search-LUT cells over [0,1]

__global__ __launch_bounds__(NTHREADS, 8) void w2loss_kernel(
    const float* __restrict__ f,
    const float* __restrict__ t,
    const float* __restrict__ knots,
    const float* __restrict__ coeffs,
    float* __restrict__ out)
{
    const int b    = blockIdx.x;
    const int tid  = threadIdx.x;
    const int lane = tid & 63;
    const int wave = tid >> 6;

    __shared__ float  s_knots[K];
    __shared__ float4 s_coeffs[K - 1];
    __shared__ int    s_lut[LUTG];
    __shared__ float  s_wsum[NWAVES];
    __shared__ float  s_wred[NWAVES];
    __shared__ float  s_f0;

    // ---- stage per-trace spline tables in LDS ----
    if (tid < K) s_knots[tid] = knots[(size_t)b * K + tid];
    if (tid < K - 1)
        s_coeffs[tid] =
            reinterpret_cast<const float4*>(coeffs + (size_t)b * (K - 1) * 4)[tid];

    // ---- load this thread's 8 contiguous f samples into registers ----
    const float4* fb4 =
        reinterpret_cast<const float4*>(f + (size_t)b * NT + tid * ELEMS);
    float fv[ELEMS];
#pragma unroll
    for (int i = 0; i < ELEMS / 4; ++i) {
        float4 v = fb4[i];
        fv[4 * i + 0] = v.x; fv[4 * i + 1] = v.y;
        fv[4 * i + 2] = v.z; fv[4 * i + 3] = v.w;
    }

    float local = 0.f;
#pragma unroll
    for (int i = 0; i < ELEMS; ++i) local += fv[i];

    // ---- inclusive wave scan of per-thread sums ----
    float scan = local;
#pragma unroll
    for (int d = 1; d < 64; d <<= 1) {
        float up = __shfl_up(scan, d, 64);
        if (lane >= d) scan += up;
    }
    if (lane == 63) s_wsum[wave] = scan;
    if (tid == 0)  s_f0 = fv[0];
    __syncthreads();                      // knots, coeffs, wsum, f0 visible

    // ---- build uniform search LUT: lut[g] = max idx with knots[idx] <= g/G ----
    if (tid < LUTG) {
        float gval = (float)tid * (1.0f / (float)LUTG);
        int p = 0;
#pragma unroll
        for (int step = 64; step >= 1; step >>= 1) {
            int np = p + step;
            if (np <= K - 1 && s_knots[np] <= gval) p = np;
        }
        s_lut[tid] = p;                   // always <= K-2 (knots[K-1] > 255/256)
    }
    __syncthreads();                      // LUT visible

    float waveoff = 0.f;
    for (int w = 0; w < wave; ++w) waveoff += s_wsum[w];   // wave-uniform loop

    const float f0      = s_f0;
    const float dt      = t[1] - t[0];    // uniform grid; t_i == i*dt
    const float half_dt = 0.5f * dt;

    // thread's first-sample CDF value from the block scan
    const float S_incl_first = waveoff + (scan - local) + fv[0];
    float F = (S_incl_first - 0.5f * (f0 + fv[0])) * dt;

    const int   base = tid * ELEMS;
    const float tb   = (float)base * dt;

    // ---- first-sample interval: LUT probe + short walk ----
    int g   = (int)(F * (float)LUTG);
    g       = g > (LUTG - 1) ? (LUTG - 1) : (g < 0 ? 0 : g);
    int idx = s_lut[g];
    while (idx < K - 2 && s_knots[idx + 1] <= F) ++idx;
    float  kn_lo = s_knots[idx];
    float  kn_hi = s_knots[idx + 1];
    float4 c     = s_coeffs[idx];

    float acc, term_first, term_last = 0.f;
    {
        float dx = F - kn_lo;
        float sp = c.x + dx * (c.y + dx * (c.z + dx * c.w));
        float d0 = tb - sp;
        term_first = d0 * d0 * fv[0];
        acc = term_first;
    }

#pragma unroll
    for (int i = 1; i < ELEMS; ++i) {
        F = fmaf(fv[i - 1] + fv[i], half_dt, F);   // exact trapezoid recurrence
        if (kn_hi <= F && idx < K - 2) {           // advance interval (rare)
            do { ++idx; kn_hi = s_knots[idx + 1]; } while (kn_hi <= F && idx < K - 2);
            kn_lo = s_knots[idx];
            c     = s_coeffs[idx];
        }
        float dx = F - kn_lo;
        float sp = c.x + dx * (c.y + dx * (c.z + dx * c.w));
        float tt = fmaf((float)i, dt, tb);
        float d  = tt - sp;
        float term = d * d * fv[i];
        acc += term;
        if (i == ELEMS - 1) term_last = term;
    }

    // endpoint trapezoid weights (0.5) applied as post-corrections
    if (base == 0)          acc -= 0.5f * term_first;
    if (base + ELEMS == NT) acc -= 0.5f * term_last;

    // ---- block reduction ----
#pragma unroll
    for (int d = 32; d >= 1; d >>= 1) acc += __shfl_down(acc, d, 64);
    if (lane == 0) s_wred[wave] = acc;
    __syncthreads();
    if (tid == 0) {
        float r = 0.f;
#pragma unroll
        for (int w = 0; w < NWAVES; ++w) r += s_wred[w];
        out[b] = r * dt;
    }
}

extern "C" void kernel_launch(void* const* d_in, const int* in_sizes, int n_in,
                              void* d_out, int out_size, void* d_ws, size_t ws_size,
                              hipStream_t stream) {
    const float* f      = (const float*)d_in[0];
    const float* t      = (const float*)d_in[1];
    const float* knots  = (const float*)d_in[2];
    const float* coeffs = (const float*)d_in[3];
    float* out          = (float*)d_out;

    const int Btr = in_sizes[0] / NT;   // 2048 traces
    w2loss_kernel<<<Btr, NTHREADS, 0, stream>>>(f, t, knots, coeffs, out);
}